// Round 9
// baseline (798.344 us; speedup 1.0000x reference)
//
#include <hip/hip_runtime.h>

typedef _Float16 f16x8 __attribute__((ext_vector_type(8)));
typedef _Float16 f16x4 __attribute__((ext_vector_type(4)));
typedef float    f32x4 __attribute__((ext_vector_type(4)));

// ---------------------------------------------------------------- helpers

__device__ __forceinline__ void async16(void* lds, const void* g) {
    __builtin_amdgcn_global_load_lds(
        (const __attribute__((address_space(1))) unsigned int*)g,
        (__attribute__((address_space(3))) unsigned int*)lds, 16, 0, 0);
}

#define MEMF() asm volatile("" ::: "memory")
__device__ __forceinline__ void BAR() { MEMF(); __builtin_amdgcn_s_barrier(); MEMF(); }
#define VMWAIT(N) asm volatile("s_waitcnt vmcnt(" #N ")" ::: "memory")
#define LGKM(N)   asm volatile("s_waitcnt lgkmcnt(" #N ")" ::: "memory")
#define SBAR0()   __builtin_amdgcn_sched_barrier(0)

// swizzled LDS fragment read within a 256x32 fp16 subtile (64B rows); byte col
// XORed by ((row>>1)&3)<<4 -> conflict-free (measured 0 SQ_LDS_BANK_CONFLICT, r4/r8)
__device__ __forceinline__ f16x8 frag_ld(const char* base, int row, int kq) {
    return *(const f16x8*)(base + row * 64 + ((kq << 4) ^ (((row >> 1) & 3) << 4)));
}

// --------------------------------------- 4-phase pipelined 256x256 GEMM (m201 port)
// A [M][K] fp16, BT [N][K] fp16, C = (A*BT^T)*alpha+beta  [M][N] fp32
// 8 waves (2Mx4N), BK=64 (2 k-half subtiles of 256x32), dbuf-2 LDS (128KiB).
// Per K-tile 4 phases = (m-half, k-half). Phase p issues the ds_reads for
// phase p+1's MFMA (register one-phase-ahead), pinned pre-MFMA by memory
// clobbers + sched_barrier(0); counted lgkm (= #reads just issued) drains the
// previous set only (per-wave FIFO). Reads drain UNDER the current MFMA
// cluster. One barrier/phase; one half-tile stage (2 gload_lds)/phase;
// counted VMWAIT(2) at ends of P1/P3 (before BAR -> cross-wave stage vis).
//
// Ledger: tile T in buf T&1. Stages: P1->T+1:A-k0, P2->T+1:B-k0, P3->T+1:A-k1,
// P4->T+1:B-k1. Read-aheads: P1:{T A-k0-mh1}, P2:{T A-k1-mh0, T B-k1},
// P3:{T A-k1-mh1}, P4:{T+1 A-k0-mh0, T+1 B-k0}. RAW: P2-top reads (T k1)
// staged T-1.P3/P4, drained by VMWAIT(2)@P1-end + BAR; P4-top reads (T+1 k0)
// staged T.P1/P2, drained by VMWAIT(2)@P3-end + BAR. WAR: each staged region's
// last reader drained >=2 phases earlier via counted lgkm before that wave's
// MFMA + trailing barriers (e.g. T+1:A-k1 region last read at T-1.P2-top,
// drained by T-1.P3's LGKM(4), two barriers before T.P3's stage).

__global__ __launch_bounds__(512, 2) void gemm_f16_bn_4ph(
        const _Float16* __restrict__ A, const _Float16* __restrict__ BT,
        float* __restrict__ C,
        const float* __restrict__ bias, const float* __restrict__ mean,
        const float* __restrict__ var,  const float* __restrict__ bnw,
        const float* __restrict__ bnb,  const float* __restrict__ scalep,
        int M, int N, int K) {
    __shared__ __align__(16) char ldsA[2 * 32768];   // [buf][khalf 16KB][256x32]
    __shared__ __align__(16) char ldsB[2 * 32768];

    // bijective XCD swizzle (grid = 1024, divisible by 8)
    const int nwg = gridDim.x;
    const int cpx = nwg >> 3;
    int bid = blockIdx.x;
    int swz = ((nwg & 7) == 0) ? (bid & 7) * cpx + (bid >> 3) : bid;
    const int ntn = N >> 8;
    const int m0 = (swz / ntn) << 8, n0 = (swz % ntn) << 8;

    const int t = threadIdx.x;
    const int lane = t & 63, wid = t >> 6;
    const int wr = wid >> 2, wc = wid & 3;          // 2M x 4N waves
    const int rr = lane & 15, kq = lane >> 4;
    const int arow = wr * 128, brow = wc * 64;

    // staging: each 256x32 half-tile = 1024 16B chunks; thread owns c0=t, c1=t+512.
    // LDS dest linear (c*16); global source col pre-XORed (both-sides involution).
    const int c0 = t, c1 = t + 512;
    const int r0 = c0 >> 2, r1 = c1 >> 2;
    const int sc0 = (((c0 & 3) << 4) ^ (((r0 >> 1) & 3) << 4)) >> 1;
    const int sc1 = (((c1 & 3) << 4) ^ (((r1 >> 1) & 3) << 4)) >> 1;
    const _Float16* gA0 = A  + (size_t)(m0 + r0) * K + sc0;
    const _Float16* gA1 = A  + (size_t)(m0 + r1) * K + sc1;
    const _Float16* gB0 = BT + (size_t)(n0 + r0) * K + sc0;
    const _Float16* gB1 = BT + (size_t)(n0 + r1) * K + sc1;

#define STG_A(NB, KH, T_) do {                                             \
    const size_t co_ = (size_t)(T_) * 64 + (KH) * 32;                      \
    char* d_ = ldsA + (NB) * 32768 + (KH) * 16384;                         \
    async16(d_ + (size_t)c0 * 16, gA0 + co_);                              \
    async16(d_ + (size_t)c1 * 16, gA1 + co_);                              \
  } while (0)
#define STG_B(NB, KH, T_) do {                                             \
    const size_t co_ = (size_t)(T_) * 64 + (KH) * 32;                      \
    char* d_ = ldsB + (NB) * 32768 + (KH) * 16384;                         \
    async16(d_ + (size_t)c0 * 16, gB0 + co_);                              \
    async16(d_ + (size_t)c1 * 16, gB1 + co_);                              \
  } while (0)

#define RD_A(DST, BUF, KH, MH)                                             \
    _Pragma("unroll")                                                      \
    for (int mi = 0; mi < 4; mi++)                                         \
      DST[mi] = frag_ld(ldsA + (BUF) * 32768 + (KH) * 16384,               \
                        arow + (MH) * 64 + mi * 16 + rr, kq)
#define RD_B(DST, BUF, KH)                                                 \
    _Pragma("unroll")                                                      \
    for (int ni = 0; ni < 4; ni++)                                         \
      DST[ni] = frag_ld(ldsB + (BUF) * 32768 + (KH) * 16384,               \
                        brow + ni * 16 + rr, kq)

#define MFMA16(MB, AF, BF)                                                 \
    __builtin_amdgcn_s_setprio(1);                                         \
    _Pragma("unroll")                                                      \
    for (int ni = 0; ni < 4; ni++) {                                       \
      _Pragma("unroll")                                                    \
      for (int mi = 0; mi < 4; mi++)                                       \
        acc[(MB) * 4 + mi][ni] = __builtin_amdgcn_mfma_f32_16x16x32_f16(   \
            AF[mi], BF[ni], acc[(MB) * 4 + mi][ni], 0, 0, 0);              \
    }                                                                      \
    __builtin_amdgcn_s_setprio(0)

    f16x8 afA[4], afB[4], bfA[4], bfB[4];
    f32x4 acc[8][4] = {};

    const int NT = K >> 6;   // host gate: >= 2

    // prologue: stage all 4 half-tiles of tile 0 into buf 0; drain; load P1 set
    STG_A(0, 0, 0); STG_B(0, 0, 0); STG_A(0, 1, 0); STG_B(0, 1, 0);
    VMWAIT(0);
    BAR();
    RD_A(afA, 0, 0, 0);      // T0 A-k0 mh0
    RD_B(bfA, 0, 0);         // T0 B-k0

    for (int T = 0; T < NT; ++T) {
        const int buf = T & 1, nbuf = buf ^ 1;
        const bool more = (T + 1) < NT;
        // ---- P1: MFMA acc[0..3] (afA x bfA, k0); read-ahead A-k0-mh1
        RD_A(afB, buf, 0, 1);
        if (more) STG_A(nbuf, 0, T + 1);
        LGKM(4); SBAR0();
        MFMA16(0, afA, bfA);
        VMWAIT(2);           // drains T-1.P3/P4 stages (T's k1 halves)
        BAR();
        // ---- P2: MFMA acc[4..7] (afB x bfA, k0); read-ahead A-k1-mh0 + B-k1
        RD_A(afA, buf, 1, 0);
        RD_B(bfB, buf, 1);
        if (more) STG_B(nbuf, 0, T + 1);
        LGKM(8); SBAR0();
        MFMA16(1, afB, bfA);
        BAR();
        // ---- P3: MFMA acc[0..3] (afA x bfB, k1); read-ahead A-k1-mh1
        RD_A(afB, buf, 1, 1);
        if (more) STG_A(nbuf, 1, T + 1);
        LGKM(4); SBAR0();
        MFMA16(0, afA, bfB);
        VMWAIT(2);           // drains T.P1/P2 stages (T+1's k0 halves)
        BAR();
        // ---- P4: MFMA acc[4..7] (afB x bfB, k1); read-ahead T+1 A-k0-mh0 + B-k0
        if (more) {
            RD_A(afA, nbuf, 0, 0);
            RD_B(bfA, nbuf, 0);
            STG_B(nbuf, 1, T + 1);
            LGKM(8);
        } else {
            LGKM(0);
        }
        SBAR0();
        MFMA16(1, afB, bfB);
        BAR();
    }
#undef STG_A
#undef STG_B
#undef RD_A
#undef RD_B
#undef MFMA16

    // fused BN-affine epilogue, nontemporal fp32 stores
    const float s = scalep[0];
    const int colb = n0 + wc * 64 + rr;
    const int rowb = m0 + wr * 128 + (kq << 2);
#pragma unroll
    for (int ni = 0; ni < 4; ni++) {
        const int col = colb + ni * 16;
        const float rv    = rsqrtf(var[col] + 1e-5f);
        const float alpha = rv * bnw[col] * s;
        const float beta  = (bias[col] - mean[col]) * alpha + bnb[col] * s;
#pragma unroll
        for (int mi = 0; mi < 8; mi++)
#pragma unroll
            for (int i = 0; i < 4; i++)
                __builtin_nontemporal_store(acc[mi][ni][i] * alpha + beta,
                    &C[(size_t)(rowb + mi * 16 + i) * N + col]);
    }
}

// ---------------------------------------------------------------- converts

__global__ __launch_bounds__(256) void cvt_x_kernel(const float4* __restrict__ in,
                                                    f16x4* __restrict__ outp, long n4) {
    long i = (long)blockIdx.x * blockDim.x + threadIdx.x;
    const long stride = (long)gridDim.x * blockDim.x;
    for (; i < n4; i += stride) {
        float4 v = in[i];
        f16x4 h = { (_Float16)v.x, (_Float16)v.y, (_Float16)v.z, (_Float16)v.w };
        outp[i] = h;
    }
}

// w [K][N] fp32 -> wt [N][K] fp16
__global__ __launch_bounds__(256) void transpose_w_kernel(const float* __restrict__ w,
                                                          _Float16* __restrict__ wt,
                                                          int K, int N) {
    __shared__ _Float16 tile[32][33];
    const int n0 = blockIdx.x * 32;
    const int k0 = blockIdx.y * 32;
    for (int i = threadIdx.y; i < 32; i += 8)
        tile[i][threadIdx.x] = (_Float16)w[(size_t)(k0 + i) * N + n0 + threadIdx.x];
    __syncthreads();
    for (int i = threadIdx.y; i < 32; i += 8)
        wt[(size_t)(n0 + i) * K + k0 + threadIdx.x] = tile[threadIdx.x][i];
}

// ------------------------------------------------- fallback GEMM (no ws)

__device__ __forceinline__ void mfma_step_128(const _Float16* As, const _Float16* Bs,
                                              f32x4 (&acc)[4][4], int lane, int wr, int wc) {
    const int kk = (lane >> 4) * 8;
    const int rr = lane & 15;
    f16x8 af[4], bf[4];
#pragma unroll
    for (int mi = 0; mi < 4; mi++)
        af[mi] = *(const f16x8*)(As + (size_t)(wr * 64 + mi * 16 + rr) * 32 + kk);
#pragma unroll
    for (int ni = 0; ni < 4; ni++)
        bf[ni] = *(const f16x8*)(Bs + (size_t)(wc * 64 + ni * 16 + rr) * 32 + kk);
#pragma unroll
    for (int mi = 0; mi < 4; mi++)
#pragma unroll
        for (int ni = 0; ni < 4; ni++)
            acc[mi][ni] = __builtin_amdgcn_mfma_f32_16x16x32_f16(af[mi], bf[ni], acc[mi][ni], 0, 0, 0);
}

__global__ __launch_bounds__(256) void gemm_f32src_bn(const float* __restrict__ X,
                                                      const float* __restrict__ W,
                                                      float* __restrict__ C,
                                                      const float* __restrict__ bias,
                                                      const float* __restrict__ mean,
                                                      const float* __restrict__ var,
                                                      const float* __restrict__ bnw,
                                                      const float* __restrict__ bnb,
                                                      const float* __restrict__ scalep,
                                                      int M, int N, int K) {
    __shared__ _Float16 As[128 * 32];
    __shared__ _Float16 Bs[128 * 32];

    const int nwg = gridDim.x;
    const int cpx = nwg >> 3;
    int bid = blockIdx.x;
    int swz = ((nwg & 7) == 0) ? (bid & 7) * cpx + (bid >> 3) : bid;
    const int ntn = N / 128;
    const int m0 = (swz / ntn) * 128, n0 = (swz % ntn) * 128;

    const int t = threadIdx.x;
    const int lane = t & 63, w = t >> 6;
    const int wr = w >> 1, wc = w & 1;

    f32x4 acc[4][4] = {};

    for (int k0 = 0; k0 < K; k0 += 32) {
        __syncthreads();
#pragma unroll
        for (int p = 0; p < 4; p++) {
            const int r = p * 32 + (t >> 3);
            const int c = (t & 7) * 4;
            float4 v = *(const float4*)&X[(size_t)(m0 + r) * K + k0 + c];
            f16x4 h = { (_Float16)v.x, (_Float16)v.y, (_Float16)v.z, (_Float16)v.w };
            *(f16x4*)&As[(size_t)r * 32 + c] = h;
        }
#pragma unroll
        for (int p = 0; p < 4; p++) {
            const int kk = p * 8 + (t >> 5);
            const int nn = (t & 31) * 4;
            float4 v = *(const float4*)&W[(size_t)(k0 + kk) * N + n0 + nn];
            Bs[(size_t)(nn + 0) * 32 + kk] = (_Float16)v.x;
            Bs[(size_t)(nn + 1) * 32 + kk] = (_Float16)v.y;
            Bs[(size_t)(nn + 2) * 32 + kk] = (_Float16)v.z;
            Bs[(size_t)(nn + 3) * 32 + kk] = (_Float16)v.w;
        }
        __syncthreads();
        mfma_step_128(As, Bs, acc, lane, wr, wc);
    }

    const float s = scalep[0];
    const int colbase = n0 + wc * 64 + (lane & 15);
    const int rowbase = m0 + wr * 64 + ((lane >> 4) << 2);
#pragma unroll
    for (int ni = 0; ni < 4; ni++) {
        const int col = colbase + ni * 16;
        const float r     = rsqrtf(var[col] + 1e-5f);
        const float alpha = r * bnw[col] * s;
        const float beta  = (bias[col] - mean[col]) * alpha + bnb[col] * s;
#pragma unroll
        for (int mi = 0; mi < 4; mi++)
#pragma unroll
            for (int i = 0; i < 4; i++)
                C[(size_t)(rowbase + mi * 16 + i) * N + col] = acc[mi][ni][i] * alpha + beta;
    }
}

// ---------------------------------------------------------------- softmax

__global__ __launch_bounds__(256) void softmax_rows(float* __restrict__ out, int N) {
    __shared__ float red[8];
    float4* p = (float4*)(out + (size_t)blockIdx.x * N);
    const int t = threadIdx.x;
    const int lane = t & 63, wid = t >> 6;

    float4 v[4];
    float mx = -3.4e38f;
#pragma unroll
    for (int i = 0; i < 4; i++) {
        v[i] = p[t + 256 * i];
        mx = fmaxf(mx, fmaxf(fmaxf(v[i].x, v[i].y), fmaxf(v[i].z, v[i].w)));
    }
#pragma unroll
    for (int off = 32; off >= 1; off >>= 1) mx = fmaxf(mx, __shfl_xor(mx, off));
    if (lane == 0) red[wid] = mx;
    __syncthreads();
    mx = fmaxf(fmaxf(red[0], red[1]), fmaxf(red[2], red[3]));

    float sum = 0.f;
#pragma unroll
    for (int i = 0; i < 4; i++) {
        v[i].x = __expf(v[i].x - mx); v[i].y = __expf(v[i].y - mx);
        v[i].z = __expf(v[i].z - mx); v[i].w = __expf(v[i].w - mx);
        sum += v[i].x + v[i].y + v[i].z + v[i].w;
    }
#pragma unroll
    for (int off = 32; off >= 1; off >>= 1) sum += __shfl_xor(sum, off);
    if (lane == 0) red[4 + wid] = sum;
    __syncthreads();
    sum = red[4] + red[5] + red[6] + red[7];

    const float inv = 1.0f / sum;
#pragma unroll
    for (int i = 0; i < 4; i++) {
        v[i].x *= inv; v[i].y *= inv; v[i].z *= inv; v[i].w *= inv;
        p[t + 256 * i] = v[i];
    }
}

// ---------------------------------------------------------------- launch

extern "C" void kernel_launch(void* const* d_in, const int* in_sizes, int n_in,
                              void* d_out, int out_size, void* d_ws, size_t ws_size,
                              hipStream_t stream) {
    const float* x     = (const float*)d_in[0];
    const float* w     = (const float*)d_in[1];
    const float* bias  = (const float*)d_in[2];
    const float* mean  = (const float*)d_in[3];
    const float* var   = (const float*)d_in[4];
    const float* bnw   = (const float*)d_in[5];
    const float* bnb   = (const float*)d_in[6];
    const float* scale = (const float*)d_in[7];
    float* out = (float*)d_out;

    const int N = in_sizes[2];
    const int K = in_sizes[1] / N;
    const int M = in_sizes[0] / K;

    const size_t xh_bytes = (size_t)M * K * sizeof(_Float16);
    const size_t wh_bytes = (size_t)N * K * sizeof(_Float16);
    const int NT = K >> 6;

    if (ws_size >= xh_bytes + wh_bytes && (M & 255) == 0 && (N & 255) == 0 &&
        (K & 63) == 0 && NT >= 2) {
        _Float16* x16 = (_Float16*)d_ws;
        _Float16* wt16 = (_Float16*)((char*)d_ws + xh_bytes);
        cvt_x_kernel<<<2048, 256, 0, stream>>>((const float4*)x, (f16x4*)x16,
                                               (long)M * K / 4);
        transpose_w_kernel<<<dim3(N / 32, K / 32), dim3(32, 8), 0, stream>>>(w, wt16, K, N);
        const int nblocks = (M >> 8) * (N >> 8);
        gemm_f16_bn_4ph<<<nblocks, 512, 0, stream>>>(x16, wt16, out, bias, mean, var,
                                                     bnw, bnb, scale, M, N, K);
    } else {
        const int nblocks = (M / 128) * (N / 128);
        gemm_f32src_bn<<<nblocks, 256, 0, stream>>>(x, w, out, bias, mean, var,
                                                    bnw, bnb, scale, M, N, K);
    }
    softmax_rows<<<M, 256, 0, stream>>>(out, N);
}

// Round 10
// 767.047 us; speedup vs baseline: 1.0408x; 1.0408x over previous
//
#include <hip/hip_runtime.h>

typedef _Float16 f16x8 __attribute__((ext_vector_type(8)));
typedef _Float16 f16x4 __attribute__((ext_vector_type(4)));
typedef float    f32x4 __attribute__((ext_vector_type(4)));

// ---------------------------------------------------------------- helpers

__device__ __forceinline__ void async16(void* lds, const void* g) {
    __builtin_amdgcn_global_load_lds(
        (const __attribute__((address_space(1))) unsigned int*)g,
        (__attribute__((address_space(3))) unsigned int*)lds, 16, 0, 0);
}

#define MEMF() asm volatile("" ::: "memory")
__device__ __forceinline__ void BAR() { MEMF(); __builtin_amdgcn_s_barrier(); MEMF(); }
#define VMWAIT(N) asm volatile("s_waitcnt vmcnt(" #N ")" ::: "memory")

// swizzled LDS fragment read: tile row-major [256 rows][64B], byte col XORed by
// ((row>>1)&3)<<4 -> conflict-free (measured 0 in SQ_LDS_BANK_CONFLICT, r4/r8)
__device__ __forceinline__ f16x8 frag_ld(const _Float16* buf, int row, int kq) {
    const char* p = (const char*)buf + row * 64 + ((kq << 4) ^ (((row >> 1) & 3) << 4));
    return *(const f16x8*)p;
}

// ------------------------------------------------- fat-wave 256x256 GEMM
// A [M][K] fp16, BT [N][K] fp16, C = (A*BT^T)*alpha+beta  [M][N] fp32
// 4 waves (2Mx2N), each owns a 128x128 output (acc = 256 VGPR, 1 wave/SIMD).
// Rationale (r4-r9 counters): MFMA+LDS+VALU run serially at 8 waves; fat
// waves cut LDS reads/CU by 33% (192->128 per K-64) and VALU similarly, so
// the serial sum shrinks. BK=32, ring-4 LDS (128KiB), r8's proven 2-barrier
// skeleton + counted vmcnt, same zero-conflict swizzle.
//
// Ledger (r8 scheme, 8 loads/tile): tile t in slot t&3; stage t+3 during t
// (A 4 loads before mid-BAR, B 4 mid-cluster). WAR: slot (t+3)&3 = tile
// t-1's slot; every wave's t-1 reads completed before BAR(end t-1), stage
// issues after => safe. RAW: VMWAIT(16) at end of t leaves {t+2,t+3}
// outstanding => tile t+1 resident for all waves after BAR. Invariant: at
// end of tile u, outstanding = {u+2,u+3} = 16. Tail peel: 8/0/none.

__global__ __launch_bounds__(256, 1) void gemm_f16_bn_fat(
        const _Float16* __restrict__ A, const _Float16* __restrict__ BT,
        float* __restrict__ C,
        const float* __restrict__ bias, const float* __restrict__ mean,
        const float* __restrict__ var,  const float* __restrict__ bnw,
        const float* __restrict__ bnb,  const float* __restrict__ scalep,
        int M, int N, int K) {
    __shared__ __align__(16) _Float16 ldsA[4][8192];   // 4 x 256x32 fp16 = 64KB
    __shared__ __align__(16) _Float16 ldsB[4][8192];   // 64KB

    // bijective XCD swizzle (grid = 1024, divisible by 8)
    const int nwg = gridDim.x;
    const int cpx = nwg >> 3;
    int bid = blockIdx.x;
    int swz = ((nwg & 7) == 0) ? (bid & 7) * cpx + (bid >> 3) : bid;
    const int ntn = N >> 8;
    const int m0 = (swz / ntn) << 8, n0 = (swz % ntn) << 8;

    const int t = threadIdx.x;                      // 0..255
    const int lane = t & 63, wid = t >> 6;          // 4 waves
    const int wr = wid >> 1, wc = wid & 1;          // 2M x 2N waves
    const int rr = lane & 15, kq = lane >> 4;
    const int arow = wr * 128, brow = wc * 128;

    // staging: 1024 16B-chunks per operand tile; thread owns chunks t+256j,
    // j=0..3 -> rows r0+64j, SAME source-col XOR for all j (64 rows = 0 mod 4
    // in the (row>>1)&3 swizzle). LDS dest linear; global source col pre-XORed
    // (both-sides involution, zero-conflict measured r4/r8).
    const int r0 = t >> 2;
    const int sc0 = (((t & 3) << 4) ^ (((r0 >> 1) & 3) << 4)) >> 1;
    const _Float16* gA = A  + (size_t)(m0 + r0) * K + sc0;
    const _Float16* gB = BT + (size_t)(n0 + r0) * K + sc0;
    char* const adst = (char*)&ldsA[0][0] + (size_t)t * 16;
    char* const bdst = (char*)&ldsB[0][0] + (size_t)t * 16;
    const size_t rowstep = (size_t)64 * K;          // 64 rows, in halfs

#define STG_A(QS, T_) do {                                                \
    const _Float16* s_ = gA + (size_t)(T_) * 32;                          \
    char* d_ = adst + (QS) * 16384;                                       \
    async16(d_,         s_);                                              \
    async16(d_ + 4096,  s_ + rowstep);                                    \
    async16(d_ + 8192,  s_ + 2 * rowstep);                                \
    async16(d_ + 12288, s_ + 3 * rowstep);                                \
  } while (0)
#define STG_B(QS, T_) do {                                                \
    const _Float16* s_ = gB + (size_t)(T_) * 32;                          \
    char* d_ = bdst + (QS) * 16384;                                       \
    async16(d_,         s_);                                              \
    async16(d_ + 4096,  s_ + rowstep);                                    \
    async16(d_ + 8192,  s_ + 2 * rowstep);                                \
    async16(d_ + 12288, s_ + 3 * rowstep);                                \
  } while (0)

    f32x4 acc[8][8] = {};                           // 256 VGPR accumulator

    const int NT = K >> 5;   // 128

    // prologue: stage tiles 0,1,2 (8 loads each, FIFO tile order)
#pragma unroll
    for (int ts = 0; ts < 3; ++ts) { STG_A(ts, ts); STG_B(ts, ts); }
    VMWAIT(16);       // own tile-0 loads done ({1,2}=16 in flight)
    BAR();            // => everyone's tile-0 loads done

#define TILE_STEP(SLOT, STAGE, KSRC, WAITSTMT)                                   \
  do {                                                                           \
    const _Float16* Ab = ldsA[SLOT];                                             \
    const _Float16* Bb = ldsB[SLOT];                                             \
    f16x8 af[8], bf[8];                                                          \
    _Pragma("unroll")                                                            \
    for (int mi = 0; mi < 8; mi++) af[mi] = frag_ld(Ab, arow + mi * 16 + rr, kq);\
    _Pragma("unroll")                                                            \
    for (int ni = 0; ni < 8; ni++) bf[ni] = frag_ld(Bb, brow + ni * 16 + rr, kq);\
    if (STAGE) STG_A((KSRC) & 3, KSRC);                                          \
    BAR();                                                                       \
    __builtin_amdgcn_s_setprio(1);                                               \
    _Pragma("unroll")                                                            \
    for (int ni = 0; ni < 4; ni++) {                                             \
      _Pragma("unroll")                                                          \
      for (int mi = 0; mi < 8; mi++)                                             \
        acc[mi][ni] = __builtin_amdgcn_mfma_f32_16x16x32_f16(                    \
            af[mi], bf[ni], acc[mi][ni], 0, 0, 0);                               \
    }                                                                            \
    if (STAGE) STG_B((KSRC) & 3, KSRC);                                          \
    _Pragma("unroll")                                                            \
    for (int ni = 4; ni < 8; ni++) {                                             \
      _Pragma("unroll")                                                          \
      for (int mi = 0; mi < 8; mi++)                                             \
        acc[mi][ni] = __builtin_amdgcn_mfma_f32_16x16x32_f16(                    \
            af[mi], bf[ni], acc[mi][ni], 0, 0, 0);                               \
    }                                                                            \
    __builtin_amdgcn_s_setprio(0);                                               \
    WAITSTMT;                                                                    \
    BAR();                                                                       \
  } while (0)

    int ti = 0;
    for (; ti < NT - 3; ++ti)
        TILE_STEP(ti & 3, 1, ti + 3, VMWAIT(16));
    TILE_STEP(ti & 3, 0, 0, VMWAIT(8)); ++ti;
    TILE_STEP(ti & 3, 0, 0, VMWAIT(0)); ++ti;
    TILE_STEP(ti & 3, 0, 0, (void)0);
#undef TILE_STEP
#undef STG_A
#undef STG_B

    // fused BN-affine epilogue, nontemporal fp32 stores
    const float s = scalep[0];
    const int colb = n0 + wc * 128 + rr;
    const int rowb = m0 + wr * 128 + (kq << 2);
#pragma unroll
    for (int ni = 0; ni < 8; ni++) {
        const int col = colb + ni * 16;
        const float rv    = rsqrtf(var[col] + 1e-5f);
        const float alpha = rv * bnw[col] * s;
        const float beta  = (bias[col] - mean[col]) * alpha + bnb[col] * s;
#pragma unroll
        for (int mi = 0; mi < 8; mi++)
#pragma unroll
            for (int i = 0; i < 4; i++)
                __builtin_nontemporal_store(acc[mi][ni][i] * alpha + beta,
                    &C[(size_t)(rowb + mi * 16 + i) * N + col]);
    }
}

// ---------------------------------------------------------------- converts

__global__ __launch_bounds__(256) void cvt_x_kernel(const float4* __restrict__ in,
                                                    f16x4* __restrict__ outp, long n4) {
    long i = (long)blockIdx.x * blockDim.x + threadIdx.x;
    const long stride = (long)gridDim.x * blockDim.x;
    for (; i < n4; i += stride) {
        float4 v = in[i];
        f16x4 h = { (_Float16)v.x, (_Float16)v.y, (_Float16)v.z, (_Float16)v.w };
        outp[i] = h;
    }
}

// w [K][N] fp32 -> wt [N][K] fp16
__global__ __launch_bounds__(256) void transpose_w_kernel(const float* __restrict__ w,
                                                          _Float16* __restrict__ wt,
                                                          int K, int N) {
    __shared__ _Float16 tile[32][33];
    const int n0 = blockIdx.x * 32;
    const int k0 = blockIdx.y * 32;
    for (int i = threadIdx.y; i < 32; i += 8)
        tile[i][threadIdx.x] = (_Float16)w[(size_t)(k0 + i) * N + n0 + threadIdx.x];
    __syncthreads();
    for (int i = threadIdx.y; i < 32; i += 8)
        wt[(size_t)(n0 + i) * K + k0 + threadIdx.x] = tile[threadIdx.x][i];
}

// ------------------------------------------------- fallback GEMM (no ws)

__device__ __forceinline__ void mfma_step_128(const _Float16* As, const _Float16* Bs,
                                              f32x4 (&acc)[4][4], int lane, int wr, int wc) {
    const int kk = (lane >> 4) * 8;
    const int rr = lane & 15;
    f16x8 af[4], bf[4];
#pragma unroll
    for (int mi = 0; mi < 4; mi++)
        af[mi] = *(const f16x8*)(As + (size_t)(wr * 64 + mi * 16 + rr) * 32 + kk);
#pragma unroll
    for (int ni = 0; ni < 4; ni++)
        bf[ni] = *(const f16x8*)(Bs + (size_t)(wc * 64 + ni * 16 + rr) * 32 + kk);
#pragma unroll
    for (int mi = 0; mi < 4; mi++)
#pragma unroll
        for (int ni = 0; ni < 4; ni++)
            acc[mi][ni] = __builtin_amdgcn_mfma_f32_16x16x32_f16(af[mi], bf[ni], acc[mi][ni], 0, 0, 0);
}

__global__ __launch_bounds__(256) void gemm_f32src_bn(const float* __restrict__ X,
                                                      const float* __restrict__ W,
                                                      float* __restrict__ C,
                                                      const float* __restrict__ bias,
                                                      const float* __restrict__ mean,
                                                      const float* __restrict__ var,
                                                      const float* __restrict__ bnw,
                                                      const float* __restrict__ bnb,
                                                      const float* __restrict__ scalep,
                                                      int M, int N, int K) {
    __shared__ _Float16 As[128 * 32];
    __shared__ _Float16 Bs[128 * 32];

    const int nwg = gridDim.x;
    const int cpx = nwg >> 3;
    int bid = blockIdx.x;
    int swz = ((nwg & 7) == 0) ? (bid & 7) * cpx + (bid >> 3) : bid;
    const int ntn = N / 128;
    const int m0 = (swz / ntn) * 128, n0 = (swz % ntn) * 128;

    const int t = threadIdx.x;
    const int lane = t & 63, w = t >> 6;
    const int wr = w >> 1, wc = w & 1;

    f32x4 acc[4][4] = {};

    for (int k0 = 0; k0 < K; k0 += 32) {
        __syncthreads();
#pragma unroll
        for (int p = 0; p < 4; p++) {
            const int r = p * 32 + (t >> 3);
            const int c = (t & 7) * 4;
            float4 v = *(const float4*)&X[(size_t)(m0 + r) * K + k0 + c];
            f16x4 h = { (_Float16)v.x, (_Float16)v.y, (_Float16)v.z, (_Float16)v.w };
            *(f16x4*)&As[(size_t)r * 32 + c] = h;
        }
#pragma unroll
        for (int p = 0; p < 4; p++) {
            const int kk = p * 8 + (t >> 5);
            const int nn = (t & 31) * 4;
            float4 v = *(const float4*)&W[(size_t)(k0 + kk) * N + n0 + nn];
            Bs[(size_t)(nn + 0) * 32 + kk] = (_Float16)v.x;
            Bs[(size_t)(nn + 1) * 32 + kk] = (_Float16)v.y;
            Bs[(size_t)(nn + 2) * 32 + kk] = (_Float16)v.z;
            Bs[(size_t)(nn + 3) * 32 + kk] = (_Float16)v.w;
        }
        __syncthreads();
        mfma_step_128(As, Bs, acc, lane, wr, wc);
    }

    const float s = scalep[0];
    const int colbase = n0 + wc * 64 + (lane & 15);
    const int rowbase = m0 + wr * 64 + ((lane >> 4) << 2);
#pragma unroll
    for (int ni = 0; ni < 4; ni++) {
        const int col = colbase + ni * 16;
        const float r     = rsqrtf(var[col] + 1e-5f);
        const float alpha = r * bnw[col] * s;
        const float beta  = (bias[col] - mean[col]) * alpha + bnb[col] * s;
#pragma unroll
        for (int mi = 0; mi < 4; mi++)
#pragma unroll
            for (int i = 0; i < 4; i++)
                C[(size_t)(rowbase + mi * 16 + i) * N + col] = acc[mi][ni][i] * alpha + beta;
    }
}

// ---------------------------------------------------------------- softmax

__global__ __launch_bounds__(256) void softmax_rows(float* __restrict__ out, int N) {
    __shared__ float red[8];
    float4* p = (float4*)(out + (size_t)blockIdx.x * N);
    const int t = threadIdx.x;
    const int lane = t & 63, wid = t >> 6;

    float4 v[4];
    float mx = -3.4e38f;
#pragma unroll
    for (int i = 0; i < 4; i++) {
        v[i] = p[t + 256 * i];
        mx = fmaxf(mx, fmaxf(fmaxf(v[i].x, v[i].y), fmaxf(v[i].z, v[i].w)));
    }
#pragma unroll
    for (int off = 32; off >= 1; off >>= 1) mx = fmaxf(mx, __shfl_xor(mx, off));
    if (lane == 0) red[wid] = mx;
    __syncthreads();
    mx = fmaxf(fmaxf(red[0], red[1]), fmaxf(red[2], red[3]));

    float sum = 0.f;
#pragma unroll
    for (int i = 0; i < 4; i++) {
        v[i].x = __expf(v[i].x - mx); v[i].y = __expf(v[i].y - mx);
        v[i].z = __expf(v[i].z - mx); v[i].w = __expf(v[i].w - mx);
        sum += v[i].x + v[i].y + v[i].z + v[i].w;
    }
#pragma unroll
    for (int off = 32; off >= 1; off >>= 1) sum += __shfl_xor(sum, off);
    if (lane == 0) red[4 + wid] = sum;
    __syncthreads();
    sum = red[4] + red[5] + red[6] + red[7];

    const float inv = 1.0f / sum;
#pragma unroll
    for (int i = 0; i < 4; i++) {
        v[i].x *= inv; v[i].y *= inv; v[i].z *= inv; v[i].w *= inv;
        p[t + 256 * i] = v[i];
    }
}

// ---------------------------------------------------------------- launch

extern "C" void kernel_launch(void* const* d_in, const int* in_sizes, int n_in,
                              void* d_out, int out_size, void* d_ws, size_t ws_size,
                              hipStream_t stream) {
    const float* x     = (const float*)d_in[0];
    const float* w     = (const float*)d_in[1];
    const float* bias  = (const float*)d_in[2];
    const float* mean  = (const float*)d_in[3];
    const float* var   = (const float*)d_in[4];
    const float* bnw   = (const float*)d_in[5];
    const float* bnb   = (const float*)d_in[6];
    const float* scale = (const float*)d_in[7];
    float* out = (float*)d_out;

    const int N = in_sizes[2];
    const int K = in_sizes[1] / N;
    const int M = in_sizes[0] / K;

    const size_t xh_bytes = (size_t)M * K * sizeof(_Float16);
    const size_t wh_bytes = (size_t)N * K * sizeof(_Float16);
    const int NT = K >> 5;

    if (ws_size >= xh_bytes + wh_bytes && (M & 255) == 0 && (N & 255) == 0 &&
        NT >= 8 && (K & 31) == 0) {
        _Float16* x16 = (_Float16*)d_ws;
        _Float16* wt16 = (_Float16*)((char*)d_ws + xh_bytes);
        cvt_x_kernel<<<2048, 256, 0, stream>>>((const float4*)x, (f16x4*)x16,
                                               (long)M * K / 4);
        transpose_w_kernel<<<dim3(N / 32, K / 32), dim3(32, 8), 0, stream>>>(w, wt16, K, N);
        const int nblocks = (M >> 8) * (N >> 8);
        gemm_f16_bn_fat<<<nblocks, 256, 0, stream>>>(x16, wt16, out, bias, mean, var,
                                                     bnw, bnb, scale, M, N, K);
    } else {
        const int nblocks = (M / 128) * (N / 128);
        gemm_f32src_bn<<<nblocks, 256, 0, stream>>>(x, w, out, bias, mean, var,
                                                    bnw, bnb, scale, M, N, K);
    }
    softmax_rows<<<M, 256, 0, stream>>>(out, N);
}